// Round 5
// baseline (459.701 us; speedup 1.0000x reference)
//
#include <hip/hip_runtime.h>

// GCN 2-layer, N=100000, F=64, H=128, O=100, out [N,1] fp32.
// out = agg(relu(agg(x)@W1 + b1) . (W2@Wl)) + (b2@Wl + bl)
// agg via CSR-by-dst GATHER with pre-scaled features (weightless edges):
//   y = dinv .* x ;  agg(x)[i] = dinv[i] * (y[i] + sum_in y[s])
// so CSR stores ONLY the src index (4 B/edge).

#define N_NODES 100000
#define F_IN 64
#define HID 128
#define OUT2 100
#define SCAN_CHUNK 1024

__global__ void hist_kernel(const int* __restrict__ dst, int* __restrict__ cnt, int E) {
    int e = blockIdx.x * blockDim.x + threadIdx.x;
    if (e < E) atomicAdd(&cnt[dst[e]], 1);
}

// Block-level exclusive scan over cnt (SCAN_CHUNK/block) + fused dinv compute.
__global__ __launch_bounds__(256) void scan1_kernel(const int* __restrict__ cnt,
                                                    int* __restrict__ row_ptr,
                                                    int* __restrict__ bsum,
                                                    float* __restrict__ dinv, int n) {
    __shared__ int lsum[256];
    int t = threadIdx.x;
    int i0 = blockIdx.x * SCAN_CHUNK + t * 4;
    int a = 0, b = 0, c = 0, d = 0;
    if (i0 < n)     a = cnt[i0];
    if (i0 + 1 < n) b = cnt[i0 + 1];
    if (i0 + 2 < n) c = cnt[i0 + 2];
    if (i0 + 3 < n) d = cnt[i0 + 3];
    if (i0 < n)     dinv[i0]     = rsqrtf((float)a + 1.0f);
    if (i0 + 1 < n) dinv[i0 + 1] = rsqrtf((float)b + 1.0f);
    if (i0 + 2 < n) dinv[i0 + 2] = rsqrtf((float)c + 1.0f);
    if (i0 + 3 < n) dinv[i0 + 3] = rsqrtf((float)d + 1.0f);
    int tsum = a + b + c + d;
    lsum[t] = tsum;
    __syncthreads();
    for (int off = 1; off < 256; off <<= 1) {
        int val = (t >= off) ? lsum[t - off] : 0;
        __syncthreads();
        lsum[t] += val;
        __syncthreads();
    }
    int excl = lsum[t] - tsum;
    if (i0 < n)     row_ptr[i0]     = excl;
    if (i0 + 1 < n) row_ptr[i0 + 1] = excl + a;
    if (i0 + 2 < n) row_ptr[i0 + 2] = excl + a + b;
    if (i0 + 3 < n) row_ptr[i0 + 3] = excl + a + b + c;
    if (t == 255) bsum[blockIdx.x] = lsum[255];
}

// Block 0: wave-parallel scan of per-block sums (nb<=128, 2/lane).
// Block 1: v = W2@Wl, c = b2.Wl + bl.
__global__ void scan2_prep_kernel(int* __restrict__ bsum, int nb,
                                  const float* __restrict__ W2, const float* __restrict__ b2,
                                  const float* __restrict__ Wl, const float* __restrict__ bl,
                                  float* __restrict__ v, float* __restrict__ c) {
    if (blockIdx.x == 0) {
        int l = threadIdx.x;  // 0..63
        if (l < 64) {
            int i0 = 2 * l;
            int a = (i0 < nb) ? bsum[i0] : 0;
            int b = (i0 + 1 < nb) ? bsum[i0 + 1] : 0;
            int s = a + b;
            int inc = s;
            #pragma unroll
            for (int off = 1; off < 64; off <<= 1) {
                int u = __shfl_up(inc, off, 64);
                if (l >= off) inc += u;
            }
            int excl = inc - s;
            if (i0 < nb)     bsum[i0]     = excl;
            if (i0 + 1 < nb) bsum[i0 + 1] = excl + a;
        }
    } else {
        int j = threadIdx.x;
        if (j < HID) {
            float acc = 0.f;
            for (int k = 0; k < OUT2; ++k) acc += W2[j * OUT2 + k] * Wl[k];
            v[j] = acc;
        }
        if (j == 0) {
            float acc = bl[0];
            for (int k = 0; k < OUT2; ++k) acc += b2[k] * Wl[k];
            *c = acc;
        }
    }
}

__global__ void scan3_kernel(int* __restrict__ row_ptr, const int* __restrict__ bsum,
                             int* __restrict__ cursor, int n, int E) {
    int i = blockIdx.x * blockDim.x + threadIdx.x;
    if (i < n) {
        int r = row_ptr[i] + bsum[i / SCAN_CHUNK];
        row_ptr[i] = r;
        cursor[i] = r;
    }
    if (i == 0) row_ptr[n] = E;
}

// y = dinv .* x, vectorized float4 (16 float4 per node)
__global__ void yscale_kernel(const float4* x4, float4* y4,
                              const float* __restrict__ dinv, int n16) {
    int i = blockIdx.x * blockDim.x + threadIdx.x;
    if (i < n16) {
        float di = dinv[i >> 4];
        float4 xv = x4[i];
        xv.x *= di; xv.y *= di; xv.z *= di; xv.w *= di;
        y4[i] = xv;
    }
}

// Scatter edges into CSR slots: csr[pos] = src  (weightless!)
__global__ void permute_kernel(const int* __restrict__ src, const int* __restrict__ dst,
                               int* __restrict__ cursor, int* __restrict__ csr, int E) {
    int e = blockIdx.x * blockDim.x + threadIdx.x;
    if (e < E) {
        int s = src[e], d = dst[e];
        int pos = atomicAdd(&cursor[d], 1);
        csr[pos] = s;
    }
}

// Fused layer 1: one wave per node, 8 waves/block sharing one W1 LDS copy.
// Gather 16 edges/iter: lane l covers edges q, q+4, q+8, q+12 (q=l>>4), each a
// float4 column load -> 4 independent loads in flight per lane.
// a = dinv[node]*(y[node] + sum_in y[s]); h = relu(a@W1+b1); zz = dinv*h.v
__global__ __launch_bounds__(512) void fused1_kernel(
    const float4* y4, const int* __restrict__ row_ptr,
    const int* __restrict__ csr, const float* __restrict__ dinv,
    const float* __restrict__ W1, const float* __restrict__ b1,
    const float* __restrict__ v, float* __restrict__ zz, int n) {
    __shared__ float lW1[F_IN * HID];  // 32 KB, shared by 8 waves
    __shared__ float lv[HID];
    int t = threadIdx.x;
    for (int i = t; i < (F_IN * HID) / 4; i += 512)
        ((float4*)lW1)[i] = ((const float4*)W1)[i];
    if (t < HID) lv[t] = v[t];
    __syncthreads();

    int lane = t & 63;
    int node = blockIdx.x * 8 + (t >> 6);
    if (node >= n) return;

    int q   = lane >> 4;   // edge sub-group 0..3
    int col = lane & 15;   // float4 column

    // self term (group 0 only)
    float4 facc = make_float4(0.f, 0.f, 0.f, 0.f);
    if (q == 0) facc = y4[node * 16 + col];

    int beg = row_ptr[node], end = row_ptr[node + 1];
    int p = beg + q;
    int s0 = (p < end)      ? csr[p]      : -1;
    int s1 = (p + 4 < end)  ? csr[p + 4]  : -1;
    int s2 = (p + 8 < end)  ? csr[p + 8]  : -1;
    int s3 = (p + 12 < end) ? csr[p + 12] : -1;
    for (int cb = beg; cb < end; cb += 16) {
        int c0 = s0, c1 = s1, c2 = s2, c3 = s3;
        int np = cb + 16 + q;
        s0 = (np < end)      ? csr[np]      : -1;   // prefetch next round
        s1 = (np + 4 < end)  ? csr[np + 4]  : -1;
        s2 = (np + 8 < end)  ? csr[np + 8]  : -1;
        s3 = (np + 12 < end) ? csr[np + 12] : -1;
        float m0 = (c0 >= 0) ? 1.f : 0.f;
        float m1 = (c1 >= 0) ? 1.f : 0.f;
        float m2 = (c2 >= 0) ? 1.f : 0.f;
        float m3 = (c3 >= 0) ? 1.f : 0.f;
        float4 a0 = y4[(c0 >= 0 ? c0 : 0) * 16 + col];
        float4 a1 = y4[(c1 >= 0 ? c1 : 0) * 16 + col];
        float4 a2 = y4[(c2 >= 0 ? c2 : 0) * 16 + col];
        float4 a3 = y4[(c3 >= 0 ? c3 : 0) * 16 + col];
        facc.x += m0 * a0.x + m1 * a1.x + m2 * a2.x + m3 * a3.x;
        facc.y += m0 * a0.y + m1 * a1.y + m2 * a2.y + m3 * a3.y;
        facc.z += m0 * a0.z + m1 * a1.z + m2 * a2.z + m3 * a3.z;
        facc.w += m0 * a0.w + m1 * a1.w + m2 * a2.w + m3 * a3.w;
    }

    // reduce the 4 edge sub-groups; then scale by dinv[node]
    facc.x += __shfl_xor(facc.x, 16, 64); facc.y += __shfl_xor(facc.y, 16, 64);
    facc.z += __shfl_xor(facc.z, 16, 64); facc.w += __shfl_xor(facc.w, 16, 64);
    facc.x += __shfl_xor(facc.x, 32, 64); facc.y += __shfl_xor(facc.y, 32, 64);
    facc.z += __shfl_xor(facc.z, 32, 64); facc.w += __shfl_xor(facc.w, 32, 64);
    float di = dinv[node];
    facc.x *= di; facc.y *= di; facc.z *= di; facc.w *= di;

    // GEMV: lane L computes h[2L], h[2L+1]
    float2 h = ((const float2*)b1)[lane];
    #pragma unroll
    for (int k0 = 0; k0 < 16; ++k0) {
        float ax = __shfl(facc.x, k0, 64);
        float ay = __shfl(facc.y, k0, 64);
        float az = __shfl(facc.z, k0, 64);
        float aw = __shfl(facc.w, k0, 64);
        float2 w0 = ((const float2*)lW1)[(4 * k0 + 0) * 64 + lane];
        float2 w1 = ((const float2*)lW1)[(4 * k0 + 1) * 64 + lane];
        float2 w2 = ((const float2*)lW1)[(4 * k0 + 2) * 64 + lane];
        float2 w3 = ((const float2*)lW1)[(4 * k0 + 3) * 64 + lane];
        h.x += ax * w0.x + ay * w1.x + az * w2.x + aw * w3.x;
        h.y += ax * w0.y + ay * w1.y + az * w2.y + aw * w3.y;
    }
    float2 vv = ((const float2*)lv)[lane];
    float hx = h.x > 0.f ? h.x : 0.f;
    float hy = h.y > 0.f ? h.y : 0.f;
    float zp = hx * vv.x + hy * vv.y;
    #pragma unroll
    for (int off = 32; off > 0; off >>= 1) zp += __shfl_xor(zp, off, 64);
    if (lane == 0) zz[node] = di * zp;
}

// Layer 2 (collapsed): out[i] = c + dinv[i]*(zz[i] + sum_in zz[s]). 16 lanes/node.
__global__ void out_kernel(const int* __restrict__ row_ptr, const int* __restrict__ csr,
                           const float* __restrict__ dinv, const float* __restrict__ zz,
                           const float* __restrict__ c, float* __restrict__ out, int n) {
    int tid = blockIdx.x * blockDim.x + threadIdx.x;
    int node = tid >> 4;
    int sub = tid & 15;
    if (node >= n) return;
    int beg = row_ptr[node], end = row_ptr[node + 1];
    float acc = 0.f;
    for (int e = beg + sub; e < end; e += 16) acc += zz[csr[e]];
    acc += __shfl_xor(acc, 1, 64);
    acc += __shfl_xor(acc, 2, 64);
    acc += __shfl_xor(acc, 4, 64);
    acc += __shfl_xor(acc, 8, 64);
    if (sub == 0) out[node] = c[0] + dinv[node] * (acc + zz[node]);
}

extern "C" void kernel_launch(void* const* d_in, const int* in_sizes, int n_in,
                              void* d_out, int out_size, void* d_ws, size_t ws_size,
                              hipStream_t stream) {
    const float* x  = (const float*)d_in[0];
    const int*   ei = (const int*)d_in[1];
    const float* W1 = (const float*)d_in[2];
    const float* b1 = (const float*)d_in[3];
    const float* W2 = (const float*)d_in[4];
    const float* b2 = (const float*)d_in[5];
    const float* Wl = (const float*)d_in[6];
    const float* bl = (const float*)d_in[7];
    float* out = (float*)d_out;

    int E = in_sizes[1] / 2;
    const int* src = ei;
    const int* dst = ei + E;

    float* ws     = (float*)d_ws;
    float* dinv   = ws;                       // N
    int*   row_ptr= (int*)(ws + N_NODES);     // N+1 (+pad)
    int*   cursor = row_ptr + N_NODES + 4;    // N   (doubles as cnt)
    int*   bsum   = cursor + N_NODES;         // 128
    float* zz     = (float*)(bsum + 128);     // N
    float* v      = zz + N_NODES;             // 128
    float* c      = v + HID;                  // 4 (pad)
    float* yb     = c + 4;                    // N*64 (16B-aligned: offset 4N+264)
    // total need: 4N + 264 + 64N + E floats
    size_t need = ((size_t)N_NODES * 68 + 264 + (size_t)E) * 4;
    float* y;
    int*   csr;
    if (ws_size >= need) {
        y = yb;
        csr = (int*)(yb + (size_t)N_NODES * F_IN);
    } else {
        // fallback: scale x in place (harness restores inputs before every launch)
        y = (float*)x;
        csr = (int*)yb;
    }

    int nscan = (N_NODES + SCAN_CHUNK - 1) / SCAN_CHUNK;  // 98

    hipMemsetAsync(cursor, 0, sizeof(int) * N_NODES, stream);  // cnt = 0
    hist_kernel<<<(E + 255) / 256, 256, 0, stream>>>(dst, cursor, E);
    scan1_kernel<<<nscan, 256, 0, stream>>>(cursor, row_ptr, bsum, dinv, N_NODES);
    scan2_prep_kernel<<<2, 128, 0, stream>>>(bsum, nscan, W2, b2, Wl, bl, v, c);
    scan3_kernel<<<(N_NODES + 255) / 256, 256, 0, stream>>>(row_ptr, bsum, cursor, N_NODES, E);
    yscale_kernel<<<(N_NODES * 16 + 255) / 256, 256, 0, stream>>>(
        (const float4*)x, (float4*)y, dinv, N_NODES * 16);
    permute_kernel<<<(E + 255) / 256, 256, 0, stream>>>(src, dst, cursor, csr, E);
    fused1_kernel<<<(N_NODES + 7) / 8, 512, 0, stream>>>(
        (const float4*)y, row_ptr, csr, dinv, W1, b1, v, zz, N_NODES);
    out_kernel<<<(N_NODES * 16 + 255) / 256, 256, 0, stream>>>(
        row_ptr, csr, dinv, zz, c, out, N_NODES);
}

// Round 6
// 442.917 us; speedup vs baseline: 1.0379x; 1.0379x over previous
//
#include <hip/hip_runtime.h>
#include <hip/hip_fp16.h>

// GCN 2-layer, N=100000, F=64, H=128, O=100, out [N,1] fp32.
// out = agg(relu(agg(x)@W1 + b1) . (W2@Wl)) + (b2@Wl + bl)
// agg via CSR-by-dst GATHER (weightless: csr stores src only, 4 B/edge).
// Path A (ws permitting): y = fp16(dinv .* x), gather 128 B/edge.
// Path B: gather fp32 x directly, per-edge w = dinv[s] (L2-resident table).

#define N_NODES 100000
#define F_IN 64
#define HID 128
#define OUT2 100
#define SCAN_CHUNK 1024

__global__ void hist_kernel(const int* __restrict__ dst, int* __restrict__ cnt, int E) {
    int e = blockIdx.x * blockDim.x + threadIdx.x;
    if (e < E) atomicAdd(&cnt[dst[e]], 1);
}

// Block-level exclusive scan over cnt (SCAN_CHUNK/block) + fused dinv compute.
__global__ __launch_bounds__(256) void scan1_kernel(const int* __restrict__ cnt,
                                                    int* __restrict__ row_ptr,
                                                    int* __restrict__ bsum,
                                                    float* __restrict__ dinv, int n) {
    __shared__ int lsum[256];
    int t = threadIdx.x;
    int i0 = blockIdx.x * SCAN_CHUNK + t * 4;
    int a = 0, b = 0, c = 0, d = 0;
    if (i0 < n)     a = cnt[i0];
    if (i0 + 1 < n) b = cnt[i0 + 1];
    if (i0 + 2 < n) c = cnt[i0 + 2];
    if (i0 + 3 < n) d = cnt[i0 + 3];
    if (i0 < n)     dinv[i0]     = rsqrtf((float)a + 1.0f);
    if (i0 + 1 < n) dinv[i0 + 1] = rsqrtf((float)b + 1.0f);
    if (i0 + 2 < n) dinv[i0 + 2] = rsqrtf((float)c + 1.0f);
    if (i0 + 3 < n) dinv[i0 + 3] = rsqrtf((float)d + 1.0f);
    int tsum = a + b + c + d;
    lsum[t] = tsum;
    __syncthreads();
    for (int off = 1; off < 256; off <<= 1) {
        int val = (t >= off) ? lsum[t - off] : 0;
        __syncthreads();
        lsum[t] += val;
        __syncthreads();
    }
    int excl = lsum[t] - tsum;
    if (i0 < n)     row_ptr[i0]     = excl;
    if (i0 + 1 < n) row_ptr[i0 + 1] = excl + a;
    if (i0 + 2 < n) row_ptr[i0 + 2] = excl + a + b;
    if (i0 + 3 < n) row_ptr[i0 + 3] = excl + a + b + c;
    if (t == 255) bsum[blockIdx.x] = lsum[255];
}

// Block 0: wave-parallel scan of per-block sums (nb<=128).
// Block 1: v = W2@Wl, c = b2.Wl + bl.
// Blocks >=2: y = fp16(dinv .* x), 1 float4 -> 1 uint2(4 half) per thread.
__global__ __launch_bounds__(256) void scan2_prep_kernel(
    int* __restrict__ bsum, int nb,
    const float* __restrict__ W2, const float* __restrict__ b2,
    const float* __restrict__ Wl, const float* __restrict__ bl,
    float* __restrict__ v, float* __restrict__ c,
    const float4* __restrict__ x4, __half2* __restrict__ y2,
    const float* __restrict__ dinv, int n16) {
    if (blockIdx.x == 0) {
        int l = threadIdx.x;  // first wave only
        if (l < 64) {
            int i0 = 2 * l;
            int a = (i0 < nb) ? bsum[i0] : 0;
            int b = (i0 + 1 < nb) ? bsum[i0 + 1] : 0;
            int s = a + b;
            int inc = s;
            #pragma unroll
            for (int off = 1; off < 64; off <<= 1) {
                int u = __shfl_up(inc, off, 64);
                if (l >= off) inc += u;
            }
            int excl = inc - s;
            if (i0 < nb)     bsum[i0]     = excl;
            if (i0 + 1 < nb) bsum[i0 + 1] = excl + a;
        }
    } else if (blockIdx.x == 1) {
        int j = threadIdx.x;
        if (j < HID) {
            float acc = 0.f;
            for (int k = 0; k < OUT2; ++k) acc += W2[j * OUT2 + k] * Wl[k];
            v[j] = acc;
        }
        if (j == 0) {
            float acc = bl[0];
            for (int k = 0; k < OUT2; ++k) acc += b2[k] * Wl[k];
            *c = acc;
        }
    } else {
        int i = (blockIdx.x - 2) * 256 + threadIdx.x;
        if (i < n16) {
            float di = dinv[i >> 4];
            float4 xv = x4[i];
            y2[2 * i]     = __floats2half2_rn(xv.x * di, xv.y * di);
            y2[2 * i + 1] = __floats2half2_rn(xv.z * di, xv.w * di);
        }
    }
}

__global__ void scan3_kernel(int* __restrict__ row_ptr, const int* __restrict__ bsum,
                             int* __restrict__ cursor, int n, int E) {
    int i = blockIdx.x * blockDim.x + threadIdx.x;
    if (i < n) {
        int r = row_ptr[i] + bsum[i / SCAN_CHUNK];
        row_ptr[i] = r;
        cursor[i] = r;
    }
    if (i == 0) row_ptr[n] = E;
}

// Scatter edges into CSR slots: csr[pos] = src (4 B/edge)
__global__ void permute_kernel(const int* __restrict__ src, const int* __restrict__ dst,
                               int* __restrict__ cursor, int* __restrict__ csr, int E) {
    int e = blockIdx.x * blockDim.x + threadIdx.x;
    if (e < E) {
        int s = src[e], d = dst[e];
        int pos = atomicAdd(&cursor[d], 1);
        csr[pos] = s;
    }
}

// ---- shared epilogue: facc holds features [4*col..4*col+3] summed over groups;
// a = di*facc; h = relu(a@W1+b1); zz = di*(h.v) --------------------------------
__device__ __forceinline__ void gemv_epilogue(
    float4 facc, float di, int lane, const float* lW1, const float* lv,
    const float* __restrict__ b1, float* __restrict__ zz, int node) {
    // reduce 4 edge sub-groups (q = lane>>4)
    facc.x += __shfl_xor(facc.x, 16, 64); facc.y += __shfl_xor(facc.y, 16, 64);
    facc.z += __shfl_xor(facc.z, 16, 64); facc.w += __shfl_xor(facc.w, 16, 64);
    facc.x += __shfl_xor(facc.x, 32, 64); facc.y += __shfl_xor(facc.y, 32, 64);
    facc.z += __shfl_xor(facc.z, 32, 64); facc.w += __shfl_xor(facc.w, 32, 64);
    facc.x *= di; facc.y *= di; facc.z *= di; facc.w *= di;

    float2 h = ((const float2*)b1)[lane];
    #pragma unroll
    for (int k0 = 0; k0 < 16; ++k0) {
        float ax = __shfl(facc.x, k0, 64);
        float ay = __shfl(facc.y, k0, 64);
        float az = __shfl(facc.z, k0, 64);
        float aw = __shfl(facc.w, k0, 64);
        float2 w0 = ((const float2*)lW1)[(4 * k0 + 0) * 64 + lane];
        float2 w1 = ((const float2*)lW1)[(4 * k0 + 1) * 64 + lane];
        float2 w2 = ((const float2*)lW1)[(4 * k0 + 2) * 64 + lane];
        float2 w3 = ((const float2*)lW1)[(4 * k0 + 3) * 64 + lane];
        h.x += ax * w0.x + ay * w1.x + az * w2.x + aw * w3.x;
        h.y += ax * w0.y + ay * w1.y + az * w2.y + aw * w3.y;
    }
    float2 vv = ((const float2*)lv)[lane];
    float hx = h.x > 0.f ? h.x : 0.f;
    float hy = h.y > 0.f ? h.y : 0.f;
    float zp = hx * vv.x + hy * vv.y;
    #pragma unroll
    for (int off = 32; off > 0; off >>= 1) zp += __shfl_xor(zp, off, 64);
    if (lane == 0) zz[node] = di * zp;
}

// Path A: fp16 pre-scaled y. One wave/node; 16 edges/iter, 4 uint2 gathers/lane.
__global__ __launch_bounds__(512) void fused1_f16_kernel(
    const uint2* __restrict__ y, const int* __restrict__ row_ptr,
    const int* __restrict__ csr, const float* __restrict__ dinv,
    const float* __restrict__ W1, const float* __restrict__ b1,
    const float* __restrict__ v, float* __restrict__ zz, int n) {
    __shared__ float lW1[F_IN * HID];
    __shared__ float lv[HID];
    int t = threadIdx.x;
    for (int i = t; i < (F_IN * HID) / 4; i += 512)
        ((float4*)lW1)[i] = ((const float4*)W1)[i];
    if (t < HID) lv[t] = v[t];
    __syncthreads();

    int lane = t & 63;
    int node = blockIdx.x * 8 + (t >> 6);
    if (node >= n) return;

    int q   = lane >> 4;
    int col = lane & 15;

    float4 facc = make_float4(0.f, 0.f, 0.f, 0.f);
    if (q == 0) {
        uint2 u = y[node * 16 + col];
        float2 f01 = __half22float2(*(const __half2*)&u.x);
        float2 f23 = __half22float2(*(const __half2*)&u.y);
        facc = make_float4(f01.x, f01.y, f23.x, f23.y);
    }

    int beg = row_ptr[node], end = row_ptr[node + 1];
    int p = beg + q;
    int s0 = (p < end)      ? csr[p]      : -1;
    int s1 = (p + 4 < end)  ? csr[p + 4]  : -1;
    int s2 = (p + 8 < end)  ? csr[p + 8]  : -1;
    int s3 = (p + 12 < end) ? csr[p + 12] : -1;
    for (int cb = beg; cb < end; cb += 16) {
        int c0 = s0, c1 = s1, c2 = s2, c3 = s3;
        int np = cb + 16 + q;
        s0 = (np < end)      ? csr[np]      : -1;
        s1 = (np + 4 < end)  ? csr[np + 4]  : -1;
        s2 = (np + 8 < end)  ? csr[np + 8]  : -1;
        s3 = (np + 12 < end) ? csr[np + 12] : -1;
        float m0 = (c0 >= 0) ? 1.f : 0.f;
        float m1 = (c1 >= 0) ? 1.f : 0.f;
        float m2 = (c2 >= 0) ? 1.f : 0.f;
        float m3 = (c3 >= 0) ? 1.f : 0.f;
        uint2 u0 = y[(c0 >= 0 ? c0 : 0) * 16 + col];
        uint2 u1 = y[(c1 >= 0 ? c1 : 0) * 16 + col];
        uint2 u2 = y[(c2 >= 0 ? c2 : 0) * 16 + col];
        uint2 u3 = y[(c3 >= 0 ? c3 : 0) * 16 + col];
        float2 a01 = __half22float2(*(const __half2*)&u0.x);
        float2 a23 = __half22float2(*(const __half2*)&u0.y);
        float2 b01 = __half22float2(*(const __half2*)&u1.x);
        float2 b23 = __half22float2(*(const __half2*)&u1.y);
        float2 c01 = __half22float2(*(const __half2*)&u2.x);
        float2 c23 = __half22float2(*(const __half2*)&u2.y);
        float2 d01 = __half22float2(*(const __half2*)&u3.x);
        float2 d23 = __half22float2(*(const __half2*)&u3.y);
        facc.x += m0 * a01.x + m1 * b01.x + m2 * c01.x + m3 * d01.x;
        facc.y += m0 * a01.y + m1 * b01.y + m2 * c01.y + m3 * d01.y;
        facc.z += m0 * a23.x + m1 * b23.x + m2 * c23.x + m3 * d23.x;
        facc.w += m0 * a23.y + m1 * b23.y + m2 * c23.y + m3 * d23.y;
    }
    gemv_epilogue(facc, dinv[node], lane, lW1, lv, b1, zz, node);
}

// Path B: fp32 x gather with per-edge w = dinv[s] (L2-resident, 400 KB).
__global__ __launch_bounds__(512) void fused1_f32_kernel(
    const float4* __restrict__ x4, const int* __restrict__ row_ptr,
    const int* __restrict__ csr, const float* __restrict__ dinv,
    const float* __restrict__ W1, const float* __restrict__ b1,
    const float* __restrict__ v, float* __restrict__ zz, int n) {
    __shared__ float lW1[F_IN * HID];
    __shared__ float lv[HID];
    int t = threadIdx.x;
    for (int i = t; i < (F_IN * HID) / 4; i += 512)
        ((float4*)lW1)[i] = ((const float4*)W1)[i];
    if (t < HID) lv[t] = v[t];
    __syncthreads();

    int lane = t & 63;
    int node = blockIdx.x * 8 + (t >> 6);
    if (node >= n) return;

    int q   = lane >> 4;
    int col = lane & 15;

    float di = dinv[node];
    float4 facc = make_float4(0.f, 0.f, 0.f, 0.f);
    if (q == 0) {
        float4 sv = x4[node * 16 + col];
        facc.x = di * sv.x; facc.y = di * sv.y; facc.z = di * sv.z; facc.w = di * sv.w;
    }

    int beg = row_ptr[node], end = row_ptr[node + 1];
    int p = beg + q;
    int s0 = (p < end)      ? csr[p]      : -1;
    int s1 = (p + 4 < end)  ? csr[p + 4]  : -1;
    int s2 = (p + 8 < end)  ? csr[p + 8]  : -1;
    int s3 = (p + 12 < end) ? csr[p + 12] : -1;
    for (int cb = beg; cb < end; cb += 16) {
        int c0 = s0, c1 = s1, c2 = s2, c3 = s3;
        int np = cb + 16 + q;
        s0 = (np < end)      ? csr[np]      : -1;
        s1 = (np + 4 < end)  ? csr[np + 4]  : -1;
        s2 = (np + 8 < end)  ? csr[np + 8]  : -1;
        s3 = (np + 12 < end) ? csr[np + 12] : -1;
        float w0 = (c0 >= 0) ? dinv[c0] : 0.f;
        float w1 = (c1 >= 0) ? dinv[c1] : 0.f;
        float w2 = (c2 >= 0) ? dinv[c2] : 0.f;
        float w3 = (c3 >= 0) ? dinv[c3] : 0.f;
        float4 a0 = x4[(c0 >= 0 ? c0 : 0) * 16 + col];
        float4 a1 = x4[(c1 >= 0 ? c1 : 0) * 16 + col];
        float4 a2 = x4[(c2 >= 0 ? c2 : 0) * 16 + col];
        float4 a3 = x4[(c3 >= 0 ? c3 : 0) * 16 + col];
        facc.x += w0 * a0.x + w1 * a1.x + w2 * a2.x + w3 * a3.x;
        facc.y += w0 * a0.y + w1 * a1.y + w2 * a2.y + w3 * a3.y;
        facc.z += w0 * a0.z + w1 * a1.z + w2 * a2.z + w3 * a3.z;
        facc.w += w0 * a0.w + w1 * a1.w + w2 * a2.w + w3 * a3.w;
    }
    gemv_epilogue(facc, di, lane, lW1, lv, b1, zz, node);
}

// Layer 2 (collapsed): out[i] = c + dinv[i]*(zz[i] + sum_in zz[s]). 16 lanes/node.
__global__ void out_kernel(const int* __restrict__ row_ptr, const int* __restrict__ csr,
                           const float* __restrict__ dinv, const float* __restrict__ zz,
                           const float* __restrict__ c, float* __restrict__ out, int n) {
    int tid = blockIdx.x * blockDim.x + threadIdx.x;
    int node = tid >> 4;
    int sub = tid & 15;
    if (node >= n) return;
    int beg = row_ptr[node], end = row_ptr[node + 1];
    float acc = 0.f;
    for (int e = beg + sub; e < end; e += 16) acc += zz[csr[e]];
    acc += __shfl_xor(acc, 1, 64);
    acc += __shfl_xor(acc, 2, 64);
    acc += __shfl_xor(acc, 4, 64);
    acc += __shfl_xor(acc, 8, 64);
    if (sub == 0) out[node] = c[0] + dinv[node] * (acc + zz[node]);
}

extern "C" void kernel_launch(void* const* d_in, const int* in_sizes, int n_in,
                              void* d_out, int out_size, void* d_ws, size_t ws_size,
                              hipStream_t stream) {
    const float* x  = (const float*)d_in[0];
    const int*   ei = (const int*)d_in[1];
    const float* W1 = (const float*)d_in[2];
    const float* b1 = (const float*)d_in[3];
    const float* W2 = (const float*)d_in[4];
    const float* b2 = (const float*)d_in[5];
    const float* Wl = (const float*)d_in[6];
    const float* bl = (const float*)d_in[7];
    float* out = (float*)d_out;

    int E = in_sizes[1] / 2;
    const int* src = ei;
    const int* dst = ei + E;

    float* ws      = (float*)d_ws;
    float* dinv    = ws;                       // N
    int*   row_ptr = (int*)(ws + N_NODES);     // N+4
    int*   cursor  = row_ptr + N_NODES + 4;    // N
    int*   bsum    = cursor + N_NODES;         // 128
    float* zz      = (float*)(bsum + 128);     // N
    float* v       = zz + N_NODES;             // 128
    float* c       = v + HID;                  // 4
    int*   csr     = (int*)(c + 4);            // E
    __half* y      = (__half*)(csr + E);       // N*64 halves (= N*32 floats)

    size_t base_floats = (size_t)N_NODES * 3 + 4 + 128 + 128 + 4 + (size_t)E;
    size_t need_f16 = (base_floats + (size_t)N_NODES * 32) * 4;
    bool use_f16 = (ws_size >= need_f16);

    int nscan = (N_NODES + SCAN_CHUNK - 1) / SCAN_CHUNK;  // 98
    int n16 = use_f16 ? N_NODES * 16 : 0;

    hipMemsetAsync(cursor, 0, sizeof(int) * N_NODES, stream);
    hist_kernel<<<(E + 255) / 256, 256, 0, stream>>>(dst, cursor, E);
    scan1_kernel<<<nscan, 256, 0, stream>>>(cursor, row_ptr, bsum, dinv, N_NODES);
    scan2_prep_kernel<<<2 + (n16 + 255) / 256, 256, 0, stream>>>(
        bsum, nscan, W2, b2, Wl, bl, v, c, (const float4*)x, (__half2*)y, dinv, n16);
    scan3_kernel<<<(N_NODES + 255) / 256, 256, 0, stream>>>(row_ptr, bsum, cursor, N_NODES, E);
    permute_kernel<<<(E + 255) / 256, 256, 0, stream>>>(src, dst, cursor, csr, E);
    if (use_f16) {
        fused1_f16_kernel<<<(N_NODES + 7) / 8, 512, 0, stream>>>(
            (const uint2*)y, row_ptr, csr, dinv, W1, b1, v, zz, N_NODES);
    } else {
        fused1_f32_kernel<<<(N_NODES + 7) / 8, 512, 0, stream>>>(
            (const float4*)x, row_ptr, csr, dinv, W1, b1, v, zz, N_NODES);
    }
    out_kernel<<<(N_NODES * 16 + 255) / 256, 256, 0, stream>>>(
        row_ptr, csr, dinv, zz, c, out, N_NODES);
}

// Round 7
// 372.603 us; speedup vs baseline: 1.2338x; 1.1887x over previous
//
#include <hip/hip_runtime.h>
#include <hip/hip_fp16.h>

// GCN 2-layer, N=100000, F=64, H=128, O=100, out [N,1] fp32.
// out = agg(relu(agg(x)@W1 + b1) . (W2@Wl)) + (b2@Wl + bl)
// agg via CSR-by-dst GATHER; layer-1 GEMV done with MFMA (fp16 split hi+lo W1).

#define N_NODES 100000
#define F_IN 64
#define HID 128
#define OUT2 100
#define SCAN_CHUNK 1024

typedef _Float16 half8 __attribute__((ext_vector_type(8)));
typedef float f32x4 __attribute__((ext_vector_type(4)));

static __device__ __forceinline__ half8 as_half8(uint4 u) {
    union { uint4 u; half8 h; } x; x.u = u; return x.h;
}

__global__ void hist_kernel(const int* __restrict__ dst, int* __restrict__ cnt, int E) {
    int e = blockIdx.x * blockDim.x + threadIdx.x;
    if (e < E) atomicAdd(&cnt[dst[e]], 1);
}

// Block-level exclusive scan over cnt (SCAN_CHUNK/block) + fused dinv compute.
__global__ __launch_bounds__(256) void scan1_kernel(const int* __restrict__ cnt,
                                                    int* __restrict__ row_ptr,
                                                    int* __restrict__ bsum,
                                                    float* __restrict__ dinv, int n) {
    __shared__ int lsum[256];
    int t = threadIdx.x;
    int i0 = blockIdx.x * SCAN_CHUNK + t * 4;
    int a = 0, b = 0, c = 0, d = 0;
    if (i0 < n)     a = cnt[i0];
    if (i0 + 1 < n) b = cnt[i0 + 1];
    if (i0 + 2 < n) c = cnt[i0 + 2];
    if (i0 + 3 < n) d = cnt[i0 + 3];
    if (i0 < n)     dinv[i0]     = rsqrtf((float)a + 1.0f);
    if (i0 + 1 < n) dinv[i0 + 1] = rsqrtf((float)b + 1.0f);
    if (i0 + 2 < n) dinv[i0 + 2] = rsqrtf((float)c + 1.0f);
    if (i0 + 3 < n) dinv[i0 + 3] = rsqrtf((float)d + 1.0f);
    int tsum = a + b + c + d;
    lsum[t] = tsum;
    __syncthreads();
    for (int off = 1; off < 256; off <<= 1) {
        int val = (t >= off) ? lsum[t - off] : 0;
        __syncthreads();
        lsum[t] += val;
        __syncthreads();
    }
    int excl = lsum[t] - tsum;
    if (i0 < n)     row_ptr[i0]     = excl;
    if (i0 + 1 < n) row_ptr[i0 + 1] = excl + a;
    if (i0 + 2 < n) row_ptr[i0 + 2] = excl + a + b;
    if (i0 + 3 < n) row_ptr[i0 + 3] = excl + a + b + c;
    if (t == 255) bsum[blockIdx.x] = lsum[255];
}

// Block 0: bsum scan (wave 0) + v = W2@Wl (threads 64..191) + c (thread 192).
// Blocks 1..8: pack W1 into MFMA B-fragment layout, fp16 hi+lo split.
// Blocks >=9: y = fp16(dinv .* x).
__global__ __launch_bounds__(256) void prep_kernel(
    int* __restrict__ bsum, int nb,
    const float* __restrict__ W1, const float* __restrict__ W2,
    const float* __restrict__ b2, const float* __restrict__ Wl,
    const float* __restrict__ bl,
    float* __restrict__ v, float* __restrict__ c,
    uint4* __restrict__ Wpk,
    const float4* __restrict__ x4, __half2* __restrict__ y2,
    const float* __restrict__ dinv, int n16) {
    int t = threadIdx.x;
    if (blockIdx.x == 0) {
        if (t < 64) {
            int i0 = 2 * t;
            int a = (i0 < nb) ? bsum[i0] : 0;
            int b = (i0 + 1 < nb) ? bsum[i0 + 1] : 0;
            int s = a + b;
            int inc = s;
            #pragma unroll
            for (int off = 1; off < 64; off <<= 1) {
                int u = __shfl_up(inc, off, 64);
                if (t >= off) inc += u;
            }
            int excl = inc - s;
            if (i0 < nb)     bsum[i0]     = excl;
            if (i0 + 1 < nb) bsum[i0 + 1] = excl + a;
        } else if (t < 192) {
            int j = t - 64;  // < 128
            float acc = 0.f;
            for (int k = 0; k < OUT2; ++k) acc += W2[j * OUT2 + k] * Wl[k];
            v[j] = acc;
        } else if (t == 192) {
            float acc = bl[0];
            for (int k = 0; k < OUT2; ++k) acc += b2[k] * Wl[k];
            *c = acc;
        }
    } else if (blockIdx.x <= 8) {
        // idx in [0,2048): bit10 = part (0=hi,1=lo), bits9..7 = cb, bit6 = kf, bits5..0 = lane
        int idx = (blockIdx.x - 1) * 256 + t;
        int lane2 = idx & 63;
        int kf    = (idx >> 6) & 1;
        int cb    = (idx >> 7) & 7;
        int part  = (idx >> 10) & 1;
        union { uint4 u; unsigned short s[8]; } pk;
        #pragma unroll
        for (int j = 0; j < 8; ++j) {
            int k    = kf * 32 + (lane2 >> 4) * 8 + j;
            int colg = cb * 16 + (lane2 & 15);
            float w = W1[k * HID + colg];
            __half h = __float2half_rn(w);
            if (part) h = __float2half_rn(w - __half2float(h));
            pk.s[j] = __half_as_ushort(h);
        }
        Wpk[idx] = pk.u;
    } else {
        int i = (blockIdx.x - 9) * 256 + t;
        if (i < n16) {
            float di = dinv[i >> 4];
            float4 xv = x4[i];
            y2[2 * i]     = __floats2half2_rn(xv.x * di, xv.y * di);
            y2[2 * i + 1] = __floats2half2_rn(xv.z * di, xv.w * di);
        }
    }
}

__global__ void scan3_kernel(int* __restrict__ row_ptr, const int* __restrict__ bsum,
                             int* __restrict__ cursor, int n, int E) {
    int i = blockIdx.x * blockDim.x + threadIdx.x;
    if (i < n) {
        int r = row_ptr[i] + bsum[i / SCAN_CHUNK];
        row_ptr[i] = r;
        cursor[i] = r;
    }
    if (i == 0) row_ptr[n] = E;
}

// Scatter edges into CSR slots: csr[pos] = src (4 B/edge)
__global__ void permute_kernel(const int* __restrict__ src, const int* __restrict__ dst,
                               int* __restrict__ cursor, int* __restrict__ csr, int E) {
    int e = blockIdx.x * blockDim.x + threadIdx.x;
    if (e < E) {
        int s = src[e], d = dst[e];
        int pos = atomicAdd(&cursor[d], 1);
        csr[pos] = s;
    }
}

// Fused layer 1: block = 4 waves = 16 nodes (one MFMA tile).
// Phase 1 (all waves): wave w gathers nodes w*4..w*4+3; lane = (q=lane>>3,
// col=lane&7); 16 rows in flight/iter (uint4 = 8 halves per load). Reduced
// row (scaled by dinv) written fp16 into LDS A-tile (MFMA A-layout, stride 9).
// Phase 2 (wave 0): 32 MFMAs (W1 hi+lo fp16 split = fp32-accurate),
// relu, dot v, write zz[16].
__global__ __launch_bounds__(256) void fused1_kernel(
    const uint4* __restrict__ y, const float4* __restrict__ x4,
    const int* __restrict__ row_ptr, const int* __restrict__ csr,
    const float* __restrict__ dinv, const uint4* __restrict__ Wpk,
    const float* __restrict__ b1, const float* __restrict__ v,
    float* __restrict__ zz, int n) {
    __shared__ uint4 Atile[16 * 9];
    int t = threadIdx.x;
    int lane = t & 63;
    int wave = t >> 6;
    int node0 = blockIdx.x * 16;
    int q = lane >> 3, col = lane & 7;

    #pragma unroll
    for (int j = 0; j < 4; ++j) {
        int m = wave * 4 + j;
        int node = node0 + m;
        float f[8];
        #pragma unroll
        for (int r = 0; r < 8; ++r) f[r] = 0.f;
        int beg = row_ptr[node], end = row_ptr[node + 1];
        if (y) {
            if (q == 0) {
                uint4 u = y[node * 8 + col];
                const __half2* hp = (const __half2*)&u;
                #pragma unroll
                for (int r = 0; r < 4; ++r) {
                    float2 fv = __half22float2(hp[r]);
                    f[2 * r] = fv.x; f[2 * r + 1] = fv.y;
                }
            }
            int p = beg + q;
            int s0 = (p < end) ? csr[p] : -1;
            int s1 = (p + 8 < end) ? csr[p + 8] : -1;
            for (int cb = beg; cb < end; cb += 16) {
                int c0 = s0, c1 = s1;
                int np = cb + 16 + q;
                s0 = (np < end) ? csr[np] : -1;
                s1 = (np + 8 < end) ? csr[np + 8] : -1;
                uint4 u0, u1;
                if (c0 >= 0) u0 = y[c0 * 8 + col];
                if (c1 >= 0) u1 = y[c1 * 8 + col];
                if (c0 >= 0) {
                    const __half2* hp = (const __half2*)&u0;
                    #pragma unroll
                    for (int r = 0; r < 4; ++r) {
                        float2 fv = __half22float2(hp[r]);
                        f[2 * r] += fv.x; f[2 * r + 1] += fv.y;
                    }
                }
                if (c1 >= 0) {
                    const __half2* hp = (const __half2*)&u1;
                    #pragma unroll
                    for (int r = 0; r < 4; ++r) {
                        float2 fv = __half22float2(hp[r]);
                        f[2 * r] += fv.x; f[2 * r + 1] += fv.y;
                    }
                }
            }
        } else {
            // fallback: fp32 x gather, per-src weight dinv[s]
            if (q == 0) {
                float di0 = dinv[node];
                float4 a = x4[node * 16 + 2 * col];
                float4 b = x4[node * 16 + 2 * col + 1];
                f[0] = di0 * a.x; f[1] = di0 * a.y; f[2] = di0 * a.z; f[3] = di0 * a.w;
                f[4] = di0 * b.x; f[5] = di0 * b.y; f[6] = di0 * b.z; f[7] = di0 * b.w;
            }
            int p = beg + q;
            int s0 = (p < end) ? csr[p] : -1;
            int s1 = (p + 8 < end) ? csr[p + 8] : -1;
            for (int cb = beg; cb < end; cb += 16) {
                int c0 = s0, c1 = s1;
                int np = cb + 16 + q;
                s0 = (np < end) ? csr[np] : -1;
                s1 = (np + 8 < end) ? csr[np + 8] : -1;
                if (c0 >= 0) {
                    float w = dinv[c0];
                    float4 a = x4[c0 * 16 + 2 * col];
                    float4 b = x4[c0 * 16 + 2 * col + 1];
                    f[0] += w * a.x; f[1] += w * a.y; f[2] += w * a.z; f[3] += w * a.w;
                    f[4] += w * b.x; f[5] += w * b.y; f[6] += w * b.z; f[7] += w * b.w;
                }
                if (c1 >= 0) {
                    float w = dinv[c1];
                    float4 a = x4[c1 * 16 + 2 * col];
                    float4 b = x4[c1 * 16 + 2 * col + 1];
                    f[0] += w * a.x; f[1] += w * a.y; f[2] += w * a.z; f[3] += w * a.w;
                    f[4] += w * b.x; f[5] += w * b.y; f[6] += w * b.z; f[7] += w * b.w;
                }
            }
        }
        #pragma unroll
        for (int off = 8; off < 64; off <<= 1) {
            #pragma unroll
            for (int r = 0; r < 8; ++r) f[r] += __shfl_xor(f[r], off, 64);
        }
        if (lane < 8) {
            float di = dinv[node];
            union { uint4 u; __half2 h[4]; } pk;
            #pragma unroll
            for (int r = 0; r < 4; ++r)
                pk.h[r] = __floats2half2_rn(di * f[2 * r], di * f[2 * r + 1]);
            Atile[m * 9 + lane] = pk.u;
        }
    }
    __syncthreads();
    if (t >= 64) return;

    // Phase 2: wave 0. A frag: lane holds A[m=lane&15][k=(lane>>4)*8+j] (+32 for A1).
    int mm = lane & 15, kq = lane >> 4;
    half8 A0 = as_half8(Atile[mm * 9 + kq]);
    half8 A1 = as_half8(Atile[mm * 9 + 4 + kq]);
    f32x4 acc[8];
    #pragma unroll
    for (int cb = 0; cb < 8; ++cb) acc[cb] = (f32x4){0.f, 0.f, 0.f, 0.f};
    #pragma unroll
    for (int cb = 0; cb < 8; ++cb) {
        half8 bh0 = as_half8(Wpk[(cb * 2 + 0) * 64 + lane]);
        half8 bh1 = as_half8(Wpk[(cb * 2 + 1) * 64 + lane]);
        half8 bl0 = as_half8(Wpk[1024 + (cb * 2 + 0) * 64 + lane]);
        half8 bl1 = as_half8(Wpk[1024 + (cb * 2 + 1) * 64 + lane]);
        acc[cb] = __builtin_amdgcn_mfma_f32_16x16x32_f16(A0, bh0, acc[cb], 0, 0, 0);
        acc[cb] = __builtin_amdgcn_mfma_f32_16x16x32_f16(A1, bh1, acc[cb], 0, 0, 0);
        acc[cb] = __builtin_amdgcn_mfma_f32_16x16x32_f16(A0, bl0, acc[cb], 0, 0, 0);
        acc[cb] = __builtin_amdgcn_mfma_f32_16x16x32_f16(A1, bl1, acc[cb], 0, 0, 0);
    }
    // C layout: col = lane&15, row = (lane>>4)*4 + reg
    float zp[4] = {0.f, 0.f, 0.f, 0.f};
    #pragma unroll
    for (int cb = 0; cb < 8; ++cb) {
        int colg = cb * 16 + mm;
        float bb = b1[colg], vv = v[colg];
        #pragma unroll
        for (int r = 0; r < 4; ++r) {
            float h = acc[cb][r] + bb;
            h = fmaxf(h, 0.f);
            zp[r] += h * vv;
        }
    }
    #pragma unroll
    for (int off = 1; off < 16; off <<= 1) {
        #pragma unroll
        for (int r = 0; r < 4; ++r) zp[r] += __shfl_xor(zp[r], off, 64);
    }
    if (mm == 0) {
        int nb = node0 + kq * 4;
        #pragma unroll
        for (int r = 0; r < 4; ++r) zz[nb + r] = dinv[nb + r] * zp[r];
    }
}

// Layer 2 (collapsed): out[i] = c + dinv[i]*(zz[i] + sum_in zz[s]). 16 lanes/node.
__global__ void out_kernel(const int* __restrict__ row_ptr, const int* __restrict__ csr,
                           const float* __restrict__ dinv, const float* __restrict__ zz,
                           const float* __restrict__ c, float* __restrict__ out, int n) {
    int tid = blockIdx.x * blockDim.x + threadIdx.x;
    int node = tid >> 4;
    int sub = tid & 15;
    if (node >= n) return;
    int beg = row_ptr[node], end = row_ptr[node + 1];
    float acc = 0.f;
    for (int e = beg + sub; e < end; e += 16) acc += zz[csr[e]];
    acc += __shfl_xor(acc, 1, 64);
    acc += __shfl_xor(acc, 2, 64);
    acc += __shfl_xor(acc, 4, 64);
    acc += __shfl_xor(acc, 8, 64);
    if (sub == 0) out[node] = c[0] + dinv[node] * (acc + zz[node]);
}

extern "C" void kernel_launch(void* const* d_in, const int* in_sizes, int n_in,
                              void* d_out, int out_size, void* d_ws, size_t ws_size,
                              hipStream_t stream) {
    const float* x  = (const float*)d_in[0];
    const int*   ei = (const int*)d_in[1];
    const float* W1 = (const float*)d_in[2];
    const float* b1 = (const float*)d_in[3];
    const float* W2 = (const float*)d_in[4];
    const float* b2 = (const float*)d_in[5];
    const float* Wl = (const float*)d_in[6];
    const float* bl = (const float*)d_in[7];
    float* out = (float*)d_out;

    int E = in_sizes[1] / 2;
    const int* src = ei;
    const int* dst = ei + E;

    float* ws      = (float*)d_ws;
    float* dinv    = ws;                       // N
    int*   row_ptr = (int*)(ws + N_NODES);     // N+4
    int*   cursor  = row_ptr + N_NODES + 4;    // N
    int*   bsum    = cursor + N_NODES;         // 128
    float* zz      = (float*)(bsum + 128);     // N
    float* v       = zz + N_NODES;             // 128
    float* c       = v + HID;                  // 4
    int*   csr     = (int*)(c + 4);            // E
    float* after   = (float*)(csr + E);
    uint4* Wpk     = (uint4*)after;            // 2048 uint4 (32 KB)
    __half* y      = (__half*)(after + 8192);  // N*64 halves

    size_t base_floats = (size_t)N_NODES * 3 + 4 + 128 + 128 + 4 + (size_t)E + 8192;
    size_t need_f16 = (base_floats + (size_t)N_NODES * 32) * 4;
    bool use_f16 = (ws_size >= need_f16);
    int n16 = use_f16 ? N_NODES * 16 : 0;

    int nscan = (N_NODES + SCAN_CHUNK - 1) / SCAN_CHUNK;  // 98
    int prep_blocks = 9 + (n16 + 255) / 256;

    hipMemsetAsync(cursor, 0, sizeof(int) * N_NODES, stream);
    hist_kernel<<<(E + 255) / 256, 256, 0, stream>>>(dst, cursor, E);
    scan1_kernel<<<nscan, 256, 0, stream>>>(cursor, row_ptr, bsum, dinv, N_NODES);
    prep_kernel<<<prep_blocks, 256, 0, stream>>>(
        bsum, nscan, W1, W2, b2, Wl, bl, v, c, Wpk,
        (const float4*)x, (__half2*)y, dinv, n16);
    scan3_kernel<<<(N_NODES + 255) / 256, 256, 0, stream>>>(row_ptr, bsum, cursor, N_NODES, E);
    permute_kernel<<<(E + 255) / 256, 256, 0, stream>>>(src, dst, cursor, csr, E);
    fused1_kernel<<<N_NODES / 16, 256, 0, stream>>>(
        use_f16 ? (const uint4*)y : nullptr, (const float4*)x,
        row_ptr, csr, dinv, Wpk, b1, v, zz, N_NODES);
    out_kernel<<<(N_NODES * 16 + 255) / 256, 256, 0, stream>>>(
        row_ptr, csr, dinv, zz, c, out, N_NODES);
}